// Round 1
// baseline (787.845 us; speedup 1.0000x reference)
//
#include <hip/hip_runtime.h>

#define NUU 8039
#define NII 32770
#define NBB 4771
#define NTOT (NUU + NII + NBB)   // 45580
#define EMB 32
#define NNZ_E 2000000
#define EPSF 1e-8f
#define L2F 1e-5f
#define NBATCH 2048
#define KB 100

__device__ __forceinline__ float get_x(const float* __restrict__ ufeat,
                                       const float* __restrict__ ifeat,
                                       const float* __restrict__ bfeat,
                                       int i, int d) {
    if (i < NUU) return ufeat[i * EMB + d];
    if (i < NUU + NII) return ifeat[(i - NUU) * EMB + d];
    return bfeat[(i - NUU - NII) * EMB + d];
}

// Degree counting: dv[r]++, de[c]++ as float (counts < 2^24, exact in f32).
__global__ void k_deg(const int* __restrict__ rows, const int* __restrict__ cols,
                      float* __restrict__ dv, float* __restrict__ de) {
    int e = blockIdx.x * blockDim.x + threadIdx.x;
    if (e < NNZ_E) {
        atomicAdd(&dv[rows[e]], 1.0f);
        atomicAdd(&de[cols[e]], 1.0f);
    }
}

__global__ void k_rsq(const float* __restrict__ dv, const float* __restrict__ de,
                      float* __restrict__ dvi, float* __restrict__ dei) {
    int i = blockIdx.x * blockDim.x + threadIdx.x;
    if (i < NTOT) {
        dvi[i] = 1.0f / (sqrtf(dv[i]) + EPSF);
        dei[i] = 1.0f / (sqrtf(de[i]) + EPSF);
    }
}

// u[c] += x[r] * dvi[r]   — thread per (edge, dim); 32-lane group per edge.
__global__ void k_scat1(const int* __restrict__ rows, const int* __restrict__ cols,
                        const float* __restrict__ ufeat, const float* __restrict__ ifeat,
                        const float* __restrict__ bfeat, const float* __restrict__ dvi,
                        float* __restrict__ u) {
    unsigned tid = blockIdx.x * blockDim.x + threadIdx.x;
    unsigned e = tid >> 5;
    int d = tid & 31;
    if (e < NNZ_E) {
        int r = rows[e], c = cols[e];
        float val = get_x(ufeat, ifeat, bfeat, r, d) * dvi[r];
        atomicAdd(&u[c * EMB + d], val);
    }
}

// v[r] += (u[c] * dei[c])  — dei fused at gather (same f32 product as reference).
__global__ void k_scat2(const int* __restrict__ rows, const int* __restrict__ cols,
                        const float* __restrict__ u, const float* __restrict__ dei,
                        float* __restrict__ v) {
    unsigned tid = blockIdx.x * blockDim.x + threadIdx.x;
    unsigned e = tid >> 5;
    int d = tid & 31;
    if (e < NNZ_E) {
        int r = rows[e], c = cols[e];
        float val = u[c * EMB + d] * dei[c];
        atomicAdd(&v[r * EMB + d], val);
    }
}

// emb = x/2 + (v*dvi)/3 written in-place over v; fused sum(emb^2) block-reduce.
__global__ void k_emb(const float* __restrict__ ufeat, const float* __restrict__ ifeat,
                      const float* __restrict__ bfeat, const float* __restrict__ dvi,
                      float* __restrict__ v, float* __restrict__ lacc) {
    int tid = blockIdx.x * blockDim.x + threadIdx.x;
    float sq = 0.0f;
    if (tid < NTOT * EMB) {
        int i = tid >> 5, d = tid & 31;
        float e = 0.5f * get_x(ufeat, ifeat, bfeat, i, d) + (v[tid] * dvi[i]) * (1.0f / 3.0f);
        v[tid] = e;
        sq = e * e;
    }
#pragma unroll
    for (int off = 32; off > 0; off >>= 1) sq += __shfl_down(sq, off, 64);
    __shared__ float smem[4];
    int lane = threadIdx.x & 63, w = threadIdx.x >> 6;
    if (lane == 0) smem[w] = sq;
    __syncthreads();
    if (threadIdx.x == 0) atomicAdd(lacc, smem[0] + smem[1] + smem[2] + smem[3]);
}

// pred[b][k] = dot32(emb[users[b]], emb[NUU+NII+bundles[b][k]])
__global__ void k_pred(const float* __restrict__ emb, const int* __restrict__ users,
                       const int* __restrict__ bundles, float* __restrict__ out) {
    int t = blockIdx.x * blockDim.x + threadIdx.x;
    if (t < NBATCH * KB) {
        int b = t / KB;
        int uidx = users[b];
        int bidx = bundles[t];
        const float4* ue = (const float4*)(emb + (size_t)uidx * EMB);
        const float4* be = (const float4*)(emb + (size_t)(NUU + NII + bidx) * EMB);
        float s = 0.0f;
#pragma unroll
        for (int j = 0; j < 8; ++j) {
            float4 a = ue[j], bb = be[j];
            s += a.x * bb.x + a.y * bb.y + a.z * bb.z + a.w * bb.w;
        }
        out[t] = s;
    }
}

__global__ void k_usb(const float* __restrict__ emb, const int* __restrict__ users,
                      const float* __restrict__ ubound, const float* __restrict__ lacc,
                      float* __restrict__ out) {
    int b = blockIdx.x * blockDim.x + threadIdx.x;
    if (b < NBATCH) {
        int uidx = users[b];
        float s = 0.0f;
#pragma unroll
        for (int d = 0; d < EMB; ++d) s += emb[uidx * EMB + d] * ubound[d];
        out[NBATCH * KB + b] = s;
    }
    if (b == 0) out[NBATCH * KB + NBATCH] = L2F * lacc[0];
}

extern "C" void kernel_launch(void* const* d_in, const int* in_sizes, int n_in,
                              void* d_out, int out_size, void* d_ws, size_t ws_size,
                              hipStream_t stream) {
    const float* ufeat  = (const float*)d_in[0];
    const float* ifeat  = (const float*)d_in[1];
    const float* bfeat  = (const float*)d_in[2];
    const float* ubound = (const float*)d_in[3];
    const int* rows     = (const int*)d_in[4];
    const int* cols     = (const int*)d_in[5];
    const int* users    = (const int*)d_in[6];
    const int* bundles  = (const int*)d_in[7];
    float* out = (float*)d_out;

    float* ws  = (float*)d_ws;
    float* dv  = ws;                   // NTOT
    float* de  = dv + NTOT;            // NTOT
    float* dvi = de + NTOT;            // NTOT
    float* dei = dvi + NTOT;           // NTOT
    float* u   = dei + NTOT;           // NTOT*EMB
    float* v   = u + (size_t)NTOT * EMB; // NTOT*EMB
    float* lacc = v + (size_t)NTOT * EMB; // 1

    size_t zero_bytes = (size_t)(4 * NTOT + 2 * NTOT * EMB + 1) * sizeof(float);
    hipMemsetAsync(d_ws, 0, zero_bytes, stream);

    k_deg<<<(NNZ_E + 255) / 256, 256, 0, stream>>>(rows, cols, dv, de);
    k_rsq<<<(NTOT + 255) / 256, 256, 0, stream>>>(dv, de, dvi, dei);
    k_scat1<<<(NNZ_E * 32 + 255) / 256, 256, 0, stream>>>(rows, cols, ufeat, ifeat, bfeat, dvi, u);
    k_scat2<<<(NNZ_E * 32 + 255) / 256, 256, 0, stream>>>(rows, cols, u, dei, v);
    k_emb<<<(NTOT * EMB + 255) / 256, 256, 0, stream>>>(ufeat, ifeat, bfeat, dvi, v, lacc);
    k_pred<<<(NBATCH * KB + 255) / 256, 256, 0, stream>>>(v, users, bundles, out);
    k_usb<<<(NBATCH + 255) / 256, 256, 0, stream>>>(v, users, ubound, lacc, out);
}